// Round 1
// baseline (227.310 us; speedup 1.0000x reference)
//
#include <hip/hip_runtime.h>

// out[b,i,j,d] = sum_{k<c} A[b,i,k,d] * B[b,k,j,d]   for i,j < c, else 0
// A: (256,64,64,32) f32, strides: b:131072, i:2048, k:32, d:1
// B: (256,64,64,32) f32, strides: b:131072, k:2048, j:32, d:1
// out same layout as A with j in place of k.

#define BATCH 256
#define NN 64
#define ND 32
#define BSTRIDE (NN * NN * ND)   // 131072
#define RSTRIDE (NN * ND)        // 2048

__global__ __launch_bounds__(512, 2) void mp_kernel(
    const float* __restrict__ A,
    const float* __restrict__ B,
    const int* __restrict__ counts,
    float* __restrict__ out)
{
    const int b = blockIdx.x;
    const int c = counts[b];
    const int tid = (int)threadIdx.x;
    const int d  = tid & 31;        // channel
    const int jg = tid >> 5;        // 0..15, group of 4 j's
    const int jb = jg << 2;         // j base

    const size_t base = (size_t)b * BSTRIDE;
    const float* __restrict__ Ab = A + base + d;                 // + i*2048 + k*32
    const float* __restrict__ Bb = B + base + (size_t)jb * ND + d; // + k*2048 + jj*32
    float* __restrict__ Ob = out + base + (size_t)jb * ND + d;     // + i*2048 + jj*32

    // wave-uniform: first j covered by this wave (wave = 2 jg groups = 8 j's)
    const bool waveActive = (((tid >> 6) << 3) < c);

    for (int i0 = 0; i0 < NN; i0 += 8) {
        float acc[8][4];
        #pragma unroll
        for (int ii = 0; ii < 8; ++ii)
            #pragma unroll
            for (int jj = 0; jj < 4; ++jj)
                acc[ii][jj] = 0.0f;

        if ((i0 < c) && waveActive) {
            const float* __restrict__ Ai = Ab + (size_t)i0 * RSTRIDE;
            #pragma unroll 2
            for (int k = 0; k < c; ++k) {
                float av[8];
                #pragma unroll
                for (int ii = 0; ii < 8; ++ii)
                    av[ii] = Ai[(size_t)ii * RSTRIDE + k * ND];
                float bv[4];
                #pragma unroll
                for (int jj = 0; jj < 4; ++jj)
                    bv[jj] = Bb[(size_t)k * RSTRIDE + jj * ND];
                #pragma unroll
                for (int ii = 0; ii < 8; ++ii)
                    #pragma unroll
                    for (int jj = 0; jj < 4; ++jj)
                        acc[ii][jj] = fmaf(av[ii], bv[jj], acc[ii][jj]);
            }
        }

        // masked store (output poisoned before timing -> must write everything)
        #pragma unroll
        for (int ii = 0; ii < 8; ++ii) {
            const int i = i0 + ii;
            const bool iv = (i < c);
            #pragma unroll
            for (int jj = 0; jj < 4; ++jj) {
                const bool v = iv && ((jb + jj) < c);
                Ob[(size_t)i * RSTRIDE + jj * ND] = v ? acc[ii][jj] : 0.0f;
            }
        }
    }
}

extern "C" void kernel_launch(void* const* d_in, const int* in_sizes, int n_in,
                              void* d_out, int out_size, void* d_ws, size_t ws_size,
                              hipStream_t stream)
{
    const float* A      = (const float*)d_in[0];
    const float* B      = (const float*)d_in[1];
    const int*   counts = (const int*)d_in[2];
    float* out = (float*)d_out;

    mp_kernel<<<dim3(BATCH), dim3(512), 0, stream>>>(A, B, counts, out);
}

// Round 2
// 98.359 us; speedup vs baseline: 2.3110x; 2.3110x over previous
//
#include <hip/hip_runtime.h>

// out[b,i,j,d] = sum_{k<c} A[b,i,k,d] * B[b,k,j,d]   for i,j < c, else 0
// A: (256,64,64,32) f32, strides: b:131072, i:2048, k:32, d:1
// B: (256,64,64,32) f32, strides: b:131072, k:2048, j:32, d:1
// out same layout as A with j in place of k.
//
// v2: grid = 8 i-chunks x 256 batches (2048 blocks, 512 thr). Fixes v1's
// occupancy (8.5% -> 1 block/CU) and the c=64 single-CU tail. Block id is
// ic*256+b so a batch's 8 blocks share blockIdx%8 -> same XCD L2 for B reuse.

#define BATCH 256
#define NN 64
#define ND 32
#define BSTRIDE (NN * NN * ND)   // 131072
#define RSTRIDE (NN * ND)        // 2048

__global__ __launch_bounds__(512, 4) void mp_kernel(
    const float* __restrict__ A,
    const float* __restrict__ B,
    const int* __restrict__ counts,
    float* __restrict__ out)
{
    const int b  = blockIdx.x & (BATCH - 1);
    const int ic = blockIdx.x >> 8;      // 0..7
    const int i0 = ic << 3;              // i-chunk base (8 rows)
    const int c  = counts[b];
    const int tid = (int)threadIdx.x;
    const int d  = tid & 31;             // channel
    const int jg = tid >> 5;             // 0..15, group of 4 j's
    const int jb = jg << 2;              // j base

    const size_t base = (size_t)b * BSTRIDE;
    float* __restrict__ Ob = out + base + (size_t)i0 * RSTRIDE + (size_t)jb * ND + d;

    // fast path: whole i-chunk is outside the valid range -> zeros
    if (i0 >= c) {
        #pragma unroll
        for (int ii = 0; ii < 8; ++ii)
            #pragma unroll
            for (int jj = 0; jj < 4; ++jj)
                Ob[(size_t)ii * RSTRIDE + jj * ND] = 0.0f;
        return;
    }

    const float* __restrict__ Ai = A + base + (size_t)i0 * RSTRIDE + d;
    const float* __restrict__ Bb = B + base + (size_t)jb * ND + d;

    float acc[8][4];
    #pragma unroll
    for (int ii = 0; ii < 8; ++ii)
        #pragma unroll
        for (int jj = 0; jj < 4; ++jj)
            acc[ii][jj] = 0.0f;

    // wave-uniform: this wave covers j's [ (tid>>6)*8, +8 ); skip compute if all >= c
    const bool waveActive = (((tid >> 6) << 3) < c);

    if (waveActive) {
        #pragma unroll 2
        for (int k = 0; k < c; ++k) {
            float av[8];
            #pragma unroll
            for (int ii = 0; ii < 8; ++ii)
                av[ii] = Ai[(size_t)ii * RSTRIDE + k * ND];
            float bv[4];
            #pragma unroll
            for (int jj = 0; jj < 4; ++jj)
                bv[jj] = Bb[(size_t)k * RSTRIDE + jj * ND];
            #pragma unroll
            for (int ii = 0; ii < 8; ++ii)
                #pragma unroll
                for (int jj = 0; jj < 4; ++jj)
                    acc[ii][jj] = fmaf(av[ii], bv[jj], acc[ii][jj]);
        }
    }

    // masked store (output poisoned before timing -> must write everything)
    #pragma unroll
    for (int ii = 0; ii < 8; ++ii) {
        const int i = i0 + ii;
        const bool iv = (i < c);
        #pragma unroll
        for (int jj = 0; jj < 4; ++jj) {
            const bool v = iv && ((jb + jj) < c);
            Ob[(size_t)ii * RSTRIDE + jj * ND] = v ? acc[ii][jj] : 0.0f;
        }
    }
}

extern "C" void kernel_launch(void* const* d_in, const int* in_sizes, int n_in,
                              void* d_out, int out_size, void* d_ws, size_t ws_size,
                              hipStream_t stream)
{
    const float* A      = (const float*)d_in[0];
    const float* B      = (const float*)d_in[1];
    const int*   counts = (const int*)d_in[2];
    float* out = (float*)d_out;

    mp_kernel<<<dim3(BATCH * 8), dim3(512), 0, stream>>>(A, B, counts, out);
}